// Round 7
// baseline (373.368 us; speedup 1.0000x reference)
//
#include <hip/hip_runtime.h>
#include <stdint.h>

#define BATCH 8
#define NPRI 100000
#define NGT 16
#define NCLS 41
#define F_POS_TH 0.5f
#define F_NEG_TH 0.4f

static constexpr int TPB = 256;
static constexpr int PBLK = (NPRI + TPB - 1) / TPB; // 391
static constexpr int HBLK = 64;    // hist blocks per batch
static constexpr int NBIN = 4096;  // 12-bit digits; key is 32-bit lc float bits

// ---- workspace layout (bytes) ----
static constexpr size_t OFF_KEY  = 0;                               // u32 [B*P] lc bits
static constexpr size_t OFF_GTC  = OFF_KEY + (size_t)BATCH*NPRI*4;  // u64 [B*16] (k_match writes all)
static constexpr size_t OFF_ZERO = OFF_GTC + BATCH*NGT*8;           // zeroed by k_init
static constexpr size_t OFF_HC   = OFF_ZERO;                        // u32 [B][4096] counts
static constexpr size_t OFF_HS   = OFF_HC + (size_t)BATCH*NBIN*4;   // f32 [B][4096] lc-sums
static constexpr size_t OFF_PREF = OFF_HS + (size_t)BATCH*NBIN*4;   // u32 [B]
static constexpr size_t OFF_TK   = OFF_PREF + BATCH*4;              // u32 [B] tickets
static constexpr size_t OFF_KREM = OFF_TK   + BATCH*4;              // u32 [B]
static constexpr size_t OFF_NPOS = OFF_KREM + BATCH*4;              // u32 [B]
static constexpr size_t OFF_SL1  = OFF_NPOS + BATCH*4;              // f32 [B]
static constexpr size_t OFF_CEP  = OFF_SL1  + BATCH*4;              // f32 [B]
static constexpr size_t OFF_NEG  = OFF_CEP  + BATCH*4;              // f32 [B]
static constexpr size_t OFF_FTK  = OFF_NEG  + BATCH*4;              // u32 [1]
static constexpr size_t OFF_END  = OFF_FTK + 4;
static constexpr size_t ZERO_BYTES = OFF_END - OFF_ZERO;
static_assert(ZERO_BYTES % 4 == 0, "zero region u32-granular");

__device__ inline float smoothl1(float d) {
  float a = fabsf(d);
  return a < 1.f ? 0.5f * d * d : a - 0.5f;
}
__device__ inline unsigned aload_u32(const unsigned* p) {
  return __hip_atomic_load(p, __ATOMIC_RELAXED, __HIP_MEMORY_SCOPE_AGENT);
}
__device__ inline float aload_f32(const float* p) {
  return __hip_atomic_load(p, __ATOMIC_RELAXED, __HIP_MEMORY_SCOPE_AGENT);
}

// ---------------- K_init: zero hist + per-batch scalars ----------------
__global__ void k_init(unsigned* __restrict__ z) {
  const int n = (int)(ZERO_BYTES / 4);
  for (int i = blockIdx.x * blockDim.x + threadIdx.x; i < n; i += gridDim.x * blockDim.x)
    z[i] = 0u;
}

// ---------------- K_match: one block per (batch, gt); argmax prior ----------------
// Streams all priors (L2-resident) with a per-thread running composite max.
// Composite (iou_bits<<32)|(~p): exact first-index argmax, no atomics.
__global__ __launch_bounds__(TPB) void k_match(const float* __restrict__ priors,
                                               const float* __restrict__ gtb,
                                               unsigned long long* __restrict__ gtc) {
  int bg = blockIdx.x;           // b*NGT + g
  int t = threadIdx.x;
  const float4 gv = ((const float4*)gtb)[bg];
  float garea = (gv.z - gv.x) * (gv.w - gv.y);
  unsigned long long best = 0;
  for (int p = t; p < NPRI; p += TPB) {
    float4 pv = ((const float4*)priors)[p];
    float px1 = pv.x - 0.5f * pv.z, py1 = pv.y - 0.5f * pv.w;
    float px2 = pv.x + 0.5f * pv.z, py2 = pv.y + 0.5f * pv.w;
    float ix = fmaxf(fminf(px2, gv.z) - fmaxf(px1, gv.x), 0.f);
    float iy = fmaxf(fminf(py2, gv.w) - fmaxf(py1, gv.y), 0.f);
    float inter = ix * iy;
    float parea = (px2 - px1) * (py2 - py1);
    float iou = inter / (parea + garea - inter);
    unsigned long long comp = ((unsigned long long)__float_as_uint(iou) << 32)
                            | (unsigned long long)(0xFFFFFFFFu - (unsigned)p);
    best = best > comp ? best : comp;
  }
#pragma unroll
  for (int off = 32; off; off >>= 1) {
    unsigned long long o = (unsigned long long)__shfl_xor((long long)best, off, 64);
    best = best > o ? best : o;
  }
  __shared__ unsigned long long red[4];
  if ((t & 63) == 0) red[t >> 6] = best;
  __syncthreads();
  if (t == 0) {
    unsigned long long r = red[0];
    r = r > red[1] ? r : red[1];
    r = r > red[2] ? r : red[2];
    r = r > red[3] ? r : red[3];
    gtc[bg] = r;
  }
}

// ---------------- K_conf: stage->LDS, then match(recompute)+force + lse/key/sl1 ----------------
// Staging FIRST with immediate LDS writes (short tmp live range); match math after
// the barrier. __launch_bounds__(,2) caps VGPR at 256 so tmp[10] can never spill.
__global__ __launch_bounds__(TPB, 2) void k_conf(
    const float* __restrict__ loc, const float* __restrict__ conf,
    const float* __restrict__ priors, const float* __restrict__ gtb,
    const int* __restrict__ gtl, const unsigned long long* __restrict__ gtc,
    unsigned* __restrict__ key,
    unsigned* __restrict__ npos, float* __restrict__ sl1sum, float* __restrict__ cepos) {
  __shared__ float rows[TPB * NCLS];
  __shared__ float red_s[4]; __shared__ unsigned red_p[4]; __shared__ float red_c[4];
  int b = blockIdx.y;
  int p0 = blockIdx.x * TPB;
  int t = threadIdx.x;
  int nrows = min(TPB, NPRI - p0);
  int n4 = nrows * NCLS / 4;  // 2624 full, 1640 tail
  const float4* src4 = (const float4*)(conf + ((size_t)b * NPRI + p0) * NCLS);
  float4* rows4 = (float4*)rows;
  if (nrows == TPB) {
    float4 tmp[10];
#pragma unroll
    for (int u = 0; u < 10; u++) tmp[u] = src4[t + u * TPB];
    // extra chunk [2560,2815]: reads at most ~19 rows past this block's 256 rows;
    // in-bounds globally (last full block ends at row 99858 < 100000).
    float4 extra = src4[10 * TPB + t];
#pragma unroll
    for (int u = 0; u < 10; u++) rows4[t + u * TPB] = tmp[u];
    if (t < n4 - 10 * TPB) rows4[10 * TPB + t] = extra;
  } else {
    for (int i = t; i < n4; i += TPB) rows4[i] = src4[i];
  }
  __syncthreads();
  int p = p0 + t;
  bool valid = p < NPRI;
  float my_sl1 = 0.f, my_ce = 0.f;
  unsigned my_pos = 0;
  if (valid) {
    // per-prior match (recomputed, bit-identical to k_match's per-iou math)
    const float4 pv = ((const float4*)priors)[p];
    float px1 = pv.x - 0.5f * pv.z, py1 = pv.y - 0.5f * pv.w;
    float px2 = pv.x + 0.5f * pv.z, py2 = pv.y + 0.5f * pv.w;
    float parea = (px2 - px1) * (py2 - py1);
    float bov = 0.f; int bidx = 0;
#pragma unroll
    for (int g = 0; g < NGT; g++) {
      const float4 gv = ((const float4*)gtb)[b * NGT + g];
      float ix = fmaxf(fminf(px2, gv.z) - fmaxf(px1, gv.x), 0.f);
      float iy = fmaxf(fminf(py2, gv.w) - fmaxf(py1, gv.y), 0.f);
      float inter = ix * iy;
      float garea = (gv.z - gv.x) * (gv.w - gv.y);
      float iou = inter / (parea + garea - inter);
      if (iou > bov) { bov = iou; bidx = g; }
    }
    float o = bov; int g = bidx;
    // force-match (last-wins over ascending g); gtc reads are block-uniform s_loads
#pragma unroll
    for (int gg = 0; gg < NGT; gg++) {
      unsigned long long c64 = gtc[b * NGT + gg];
      unsigned pw = 0xFFFFFFFFu - (unsigned)(c64 & 0xFFFFFFFFull);
      if ((unsigned)p == pw) { o = 2.0f; g = gg; }
    }
    int c = gtl[b * NGT + g];
    if (o < F_POS_TH) c = -1;
    if (o < F_NEG_TH) c = 0;
    const float* r = rows + t * NCLS;  // stride 41 floats: odd -> conflict-free
    float s = 0.f, r0 = 0.f, rc = 0.f;
#pragma unroll
    for (int j = 0; j < NCLS; j++) {   // |x|<~7 for N(0,1): direct exp-sum safe in f32
      float v = r[j];
      s += __expf(v);
      if (j == 0) r0 = v;
      if (j == c) rc = v;
    }
    float lse = __logf(s);
    // key = lc float bits (bg only). Ties contribute equal sums -> no p-tiebreak needed.
    key[(size_t)b * NPRI + p] = (c == 0) ? __float_as_uint(lse - r0) : 0u;
    if (c > 0) {
      my_pos = 1;
      my_ce = lse - rc;
      const float4 gvb = ((const float4*)gtb)[b * NGT + g];
      float tx = ((gvb.x + gvb.z) * 0.5f - pv.x) / (0.1f * pv.z);
      float ty = ((gvb.y + gvb.w) * 0.5f - pv.y) / (0.1f * pv.w);
      float tw = __logf(fmaxf((gvb.z - gvb.x) / pv.z, 1e-8f)) / 0.2f;
      float th = __logf(fmaxf((gvb.w - gvb.y) / pv.w, 1e-8f)) / 0.2f;
      const float4 ld = ((const float4*)loc)[(size_t)b * NPRI + p];
      my_sl1 = smoothl1(ld.x - tx) + smoothl1(ld.y - ty)
             + smoothl1(ld.z - tw) + smoothl1(ld.w - th);
    }
  }
  // block-level reduction, one atomic per block per counter
  float vs = my_sl1, vc = my_ce; unsigned vp = my_pos;
#pragma unroll
  for (int off = 32; off; off >>= 1) {
    vs += __shfl_down(vs, off, 64);
    vc += __shfl_down(vc, off, 64);
    vp += __shfl_down(vp, off, 64);
  }
  if ((t & 63) == 0) { red_s[t >> 6] = vs; red_c[t >> 6] = vc; red_p[t >> 6] = vp; }
  __syncthreads();
  if (t == 0) {
    float ts = red_s[0] + red_s[1] + red_s[2] + red_s[3];
    float tc = red_c[0] + red_c[1] + red_c[2] + red_c[3];
    unsigned tp = red_p[0] + red_p[1] + red_p[2] + red_p[3];
    if (tp) atomicAdd(&npos[b], tp);
    if (ts != 0.f) atomicAdd(&sl1sum[b], ts);
    if (tc != 0.f) atomicAdd(&cepos[b], tc);
  }
}

// ---------------- radix-select pass over 32-bit keys: hist + last-block select ----------------
// Pass shifts {20, 8, 0}; active iff key>>(shift+12) == prefix>>(shift+12) (u64-promoted so
// shift 32 is defined). negsum accumulates Sum(lc) over definitively-included items each pass;
// final pass adds the threshold bin fractionally (exact under ties).
__global__ __launch_bounds__(256) void k_histfine(
    const unsigned* __restrict__ key,
    unsigned* __restrict__ hc_g, float* __restrict__ hs_g,
    unsigned* __restrict__ ticket, unsigned* __restrict__ prefix,
    unsigned* __restrict__ krem, const unsigned* __restrict__ npos,
    float* __restrict__ negsum, const float* __restrict__ sl1sum,
    const float* __restrict__ cepos, unsigned* __restrict__ final_tk,
    float* __restrict__ out, int shift, int pass) {
  __shared__ unsigned hc[NBIN];
  __shared__ float hs[NBIN];
  __shared__ unsigned pc[256]; __shared__ float ps[256];
  __shared__ unsigned sc[256]; __shared__ float ss[256];
  __shared__ int wA; __shared__ unsigned kexA; __shared__ float aboveA;
  __shared__ unsigned rk;
  int b = blockIdx.y;
  int t = threadIdx.x;
  for (int i = t; i < NBIN; i += 256) { hc[i] = 0; hs[i] = 0.f; }
  __syncthreads();
  unsigned long long pre = (unsigned long long)prefix[b] >> (shift + 12);
  for (int i = blockIdx.x * 256 + t; i < NPRI; i += HBLK * 256) {
    unsigned kk = key[(size_t)b * NPRI + i];
    if (((unsigned long long)kk >> (shift + 12)) == pre) {
      unsigned d = (kk >> shift) & 0xFFFu;
      atomicAdd(&hc[d], 1u);
      atomicAdd(&hs[d], __uint_as_float(kk));  // kk IS the lc float bits
    }
  }
  __syncthreads();
  unsigned base = ((unsigned)b) << 12;
  for (int i = t; i < NBIN; i += 256) {
    unsigned c = hc[i]; if (c) atomicAdd(&hc_g[base + i], c);
    float sv = hs[i];   if (sv != 0.f) atomicAdd(&hs_g[base + i], sv);
  }
  __threadfence();
  if (t == 0) rk = atomicAdd(&ticket[b], 1u);
  __syncthreads();
  if (rk != HBLK - 1) return;
  // ---- last block of this batch: select digit ----
  __threadfence();
  unsigned k = (pass == 0) ? min(3u * npos[b], (unsigned)(NPRI - 1)) : krem[b];
  for (int i = t; i < NBIN; i += 256) {  // pull global hist, self-clean for next pass/replay
    hc[i] = aload_u32(&hc_g[base + i]);
    hs[i] = aload_f32(&hs_g[base + i]);
    hc_g[base + i] = 0u;
    hs_g[base + i] = 0.f;
  }
  if (t == 0) { ticket[b] = 0; wA = -1; }
  __syncthreads();
  unsigned cs = 0; float fs = 0.f;
#pragma unroll
  for (int u = 0; u < 16; u++) { cs += hc[t * 16 + u]; fs += hs[t * 16 + u]; }
  pc[t] = cs; sc[t] = cs; ps[t] = fs; ss[t] = fs;
  __syncthreads();
  for (int off = 1; off < 256; off <<= 1) {  // suffix scans (count + sum)
    unsigned v = (t + off < 256) ? sc[t + off] : 0;
    float fv = (t + off < 256) ? ss[t + off] : 0.f;
    __syncthreads();
    sc[t] += v; ss[t] += fv;
    __syncthreads();
  }
  unsigned excl = sc[t] - pc[t];
  if (k > 0 && excl < k && k <= excl + pc[t]) {
    wA = t; kexA = excl; aboveA = ss[t] - ps[t];
  }
  __syncthreads();
  if (wA >= 0 && t < 64) {
    int w = wA; unsigned exw = kexA;
    unsigned v = (t < 16) ? hc[w * 16 + t] : 0;
    float fv = (t < 16) ? hs[w * 16 + t] : 0.f;
    unsigned sufv = v; float suff = fv;
#pragma unroll
    for (int off = 1; off < 16; off <<= 1) {
      unsigned x = __shfl_down(sufv, off, 64);
      float xf = __shfl_down(suff, off, 64);
      if (t + off < 16) { sufv += x; suff += xf; }
    }
    unsigned excl2 = exw + (sufv - v);
    if (t < 16 && excl2 < k && k <= excl2 + v) {
      float contrib = aboveA + (suff - fv);  // strictly-above items
      if (pass == 2) {
        contrib += (fv / (float)v) * (float)(k - excl2);  // threshold bin, exact under ties
      } else {
        prefix[b] |= ((unsigned)(w * 16 + t)) << shift;
        krem[b] = k - excl2;
      }
      if (contrib != 0.f) atomicAdd(&negsum[b], contrib);
    }
  }
  if (pass == 2) {  // globally-last block combines the final loss
    __syncthreads();
    if (t == 0) {
      __threadfence();
      unsigned r2 = atomicAdd(final_tk, 1u);
      if (r2 == BATCH - 1) {
        __threadfence();
        float lb = 0.f, ctot = 0.f;
        unsigned tp = 0;
        for (int bb = 0; bb < BATCH; bb++) {
          float ns = aload_f32(&negsum[bb]);
          lb += aload_f32(&sl1sum[bb]) / fmaxf((float)npos[bb], 1.f);
          tp += npos[bb];
          ctot += aload_f32(&cepos[bb]) + ns;
        }
        out[0] = (1.5f * lb + ctot / fmaxf((float)tp, 1.f)) / (float)BATCH;
        *final_tk = 0;  // self-clean for next replay
      }
    }
  }
}

extern "C" void kernel_launch(void* const* d_in, const int* in_sizes, int n_in,
                              void* d_out, int out_size, void* d_ws, size_t ws_size,
                              hipStream_t stream) {
  const float* loc = (const float*)d_in[0];
  const float* conf = (const float*)d_in[1];
  const float* priors = (const float*)d_in[2];
  const float* gtb = (const float*)d_in[3];
  const int* gtl = (const int*)d_in[4];
  char* ws = (char*)d_ws;
  unsigned* key = (unsigned*)(ws + OFF_KEY);
  unsigned long long* gtc = (unsigned long long*)(ws + OFF_GTC);
  unsigned* hc_g = (unsigned*)(ws + OFF_HC);
  float* hs_g = (float*)(ws + OFF_HS);
  unsigned* prefix = (unsigned*)(ws + OFF_PREF);
  unsigned* ticket = (unsigned*)(ws + OFF_TK);
  unsigned* krem = (unsigned*)(ws + OFF_KREM);
  unsigned* npos = (unsigned*)(ws + OFF_NPOS);
  float* sl1sum = (float*)(ws + OFF_SL1);
  float* cepos = (float*)(ws + OFF_CEP);
  float* negsum = (float*)(ws + OFF_NEG);
  unsigned* final_tk = (unsigned*)(ws + OFF_FTK);
  float* out = (float*)d_out;

  k_init<<<64, TPB, 0, stream>>>((unsigned*)(ws + OFF_ZERO));
  k_match<<<BATCH * NGT, TPB, 0, stream>>>(priors, gtb, gtc);
  dim3 gridP(PBLK, BATCH);
  k_conf<<<gridP, TPB, 0, stream>>>(loc, conf, priors, gtb, gtl, gtc,
                                    key, npos, sl1sum, cepos);
  dim3 gridH(HBLK, BATCH);
  const int shifts[3] = {20, 8, 0};
  for (int pass = 0; pass < 3; pass++) {
    k_histfine<<<gridH, 256, 0, stream>>>(key, hc_g, hs_g, ticket, prefix, krem,
                                          npos, negsum, sl1sum, cepos, final_tk,
                                          out, shifts[pass], pass);
  }
}

// Round 8
// 274.836 us; speedup vs baseline: 1.3585x; 1.3585x over previous
//
#include <hip/hip_runtime.h>
#include <stdint.h>

#define BATCH 8
#define NPRI 100000
#define NGT 16
#define NCLS 41
#define F_POS_TH 0.5f
#define F_NEG_TH 0.4f

static constexpr int TPB = 256;
static constexpr int PBLK = (NPRI + TPB - 1) / TPB; // 391
static constexpr int HBLK = 64;    // hist blocks per batch
static constexpr int NBIN = 4096;  // 12-bit digits; key is 32-bit lc float bits
static constexpr int MCHUNK = 16;  // prior-chunks per (b,g) in k_match
static constexpr int MLEN = (NPRI + MCHUNK - 1) / MCHUNK; // 6250

// ---- workspace layout (bytes) ----
static constexpr size_t OFF_KEY  = 0;                               // u32 [B*P] lc bits
static constexpr size_t OFF_GTC  = OFF_KEY + (size_t)BATCH*NPRI*4;  // u64 [B*16]
static constexpr size_t OFF_ZERO = OFF_GTC + BATCH*NGT*8;           // zeroed by k_init
static constexpr size_t OFF_HC   = OFF_ZERO;                        // u32 [B][4096] counts
static constexpr size_t OFF_HS   = OFF_HC + (size_t)BATCH*NBIN*4;   // f32 [B][4096] lc-sums
static constexpr size_t OFF_PREF = OFF_HS + (size_t)BATCH*NBIN*4;   // u32 [B]
static constexpr size_t OFF_TK   = OFF_PREF + BATCH*4;              // u32 [B] tickets
static constexpr size_t OFF_KREM = OFF_TK   + BATCH*4;              // u32 [B]
static constexpr size_t OFF_NPOS = OFF_KREM + BATCH*4;              // u32 [B]
static constexpr size_t OFF_SL1  = OFF_NPOS + BATCH*4;              // f32 [B]
static constexpr size_t OFF_CEP  = OFF_SL1  + BATCH*4;              // f32 [B]
static constexpr size_t OFF_NEG  = OFF_CEP  + BATCH*4;              // f32 [B]
static constexpr size_t OFF_FTK  = OFF_NEG  + BATCH*4;              // u32 [1]
static constexpr size_t OFF_END  = OFF_FTK + 4;
static constexpr size_t ZERO_BYTES = OFF_END - OFF_ZERO;
static_assert(ZERO_BYTES % 4 == 0, "zero region u32-granular");

__device__ inline float smoothl1(float d) {
  float a = fabsf(d);
  return a < 1.f ? 0.5f * d * d : a - 0.5f;
}
__device__ inline unsigned aload_u32(const unsigned* p) {
  return __hip_atomic_load(p, __ATOMIC_RELAXED, __HIP_MEMORY_SCOPE_AGENT);
}
__device__ inline float aload_f32(const float* p) {
  return __hip_atomic_load(p, __ATOMIC_RELAXED, __HIP_MEMORY_SCOPE_AGENT);
}

// ---------------- K_init: zero hist/scalars + gtc baseline ----------------
// gtc MUST be re-based every call: harness poisons ws to 0xAA once, and the
// poison pattern exceeds every real composite, so atomicMax would keep it.
__global__ void k_init(unsigned* __restrict__ z, unsigned long long* __restrict__ gtc) {
  const int n = (int)(ZERO_BYTES / 4);
  for (int i = blockIdx.x * blockDim.x + threadIdx.x; i < n; i += gridDim.x * blockDim.x)
    z[i] = 0u;
  if (blockIdx.x == 0 && threadIdx.x < BATCH * NGT)
    gtc[threadIdx.x] = 0xFFFFFFFFull;  // (iou=0)<<32 | (0xFFFFFFFF - p=0)
}

// ---------------- K_match: grid (chunk, b*g); tree-reduce, 1 atomic/block ----------------
// 2048 blocks (8/CU): ample TLP; ~25 independent iters/thread: ample ILP.
// Composite (iou_bits<<32)|(~p) == lexicographic (iou, -p) max == first-index argmax.
__global__ __launch_bounds__(TPB) void k_match(const float* __restrict__ priors,
                                               const float* __restrict__ gtb,
                                               unsigned long long* __restrict__ gtc) {
  int bg = blockIdx.y;           // b*NGT + g
  int t = threadIdx.x;
  const float4 gv = ((const float4*)gtb)[bg];
  float garea = (gv.z - gv.x) * (gv.w - gv.y);
  int pend = min(NPRI, (int)(blockIdx.x + 1) * MLEN);
  unsigned long long best = 0;
  for (int p = blockIdx.x * MLEN + t; p < pend; p += TPB) {
    float4 pv = ((const float4*)priors)[p];
    float px1 = pv.x - 0.5f * pv.z, py1 = pv.y - 0.5f * pv.w;
    float px2 = pv.x + 0.5f * pv.z, py2 = pv.y + 0.5f * pv.w;
    float ix = fmaxf(fminf(px2, gv.z) - fmaxf(px1, gv.x), 0.f);
    float iy = fmaxf(fminf(py2, gv.w) - fmaxf(py1, gv.y), 0.f);
    float inter = ix * iy;
    float parea = (px2 - px1) * (py2 - py1);
    float iou = inter / (parea + garea - inter);
    unsigned long long comp = ((unsigned long long)__float_as_uint(iou) << 32)
                            | (unsigned long long)(0xFFFFFFFFu - (unsigned)p);
    best = best > comp ? best : comp;
  }
#pragma unroll
  for (int off = 32; off; off >>= 1) {
    unsigned long long o = (unsigned long long)__shfl_xor((long long)best, off, 64);
    best = best > o ? best : o;
  }
  __shared__ unsigned long long red[4];
  if ((t & 63) == 0) red[t >> 6] = best;
  __syncthreads();
  if (t == 0) {
    unsigned long long r = red[0];
    r = r > red[1] ? r : red[1];
    r = r > red[2] ? r : red[2];
    r = r > red[3] ? r : red[3];
    atomicMax(&gtc[bg], r);
  }
}

// ---------------- K_conf: stage->LDS, then match(recompute)+force + lse/key/sl1 ----------------
// __launch_bounds__(,2) caps VGPR at 256 so the tmp[10] staging can never spill.
__global__ __launch_bounds__(TPB, 2) void k_conf(
    const float* __restrict__ loc, const float* __restrict__ conf,
    const float* __restrict__ priors, const float* __restrict__ gtb,
    const int* __restrict__ gtl, const unsigned long long* __restrict__ gtc,
    unsigned* __restrict__ key,
    unsigned* __restrict__ npos, float* __restrict__ sl1sum, float* __restrict__ cepos) {
  __shared__ float rows[TPB * NCLS];
  __shared__ float red_s[4]; __shared__ unsigned red_p[4]; __shared__ float red_c[4];
  int b = blockIdx.y;
  int p0 = blockIdx.x * TPB;
  int t = threadIdx.x;
  int nrows = min(TPB, NPRI - p0);
  int n4 = nrows * NCLS / 4;  // 2624 full, 1640 tail
  const float4* src4 = (const float4*)(conf + ((size_t)b * NPRI + p0) * NCLS);
  float4* rows4 = (float4*)rows;
  if (nrows == TPB) {
    float4 tmp[10];
#pragma unroll
    for (int u = 0; u < 10; u++) tmp[u] = src4[t + u * TPB];
    // extra chunk [2560,2815]: reads at most ~19 rows past this block's 256 rows;
    // in-bounds globally (last full block ends at row 99858 < 100000).
    float4 extra = src4[10 * TPB + t];
#pragma unroll
    for (int u = 0; u < 10; u++) rows4[t + u * TPB] = tmp[u];
    if (t < n4 - 10 * TPB) rows4[10 * TPB + t] = extra;
  } else {
    for (int i = t; i < n4; i += TPB) rows4[i] = src4[i];
  }
  __syncthreads();
  int p = p0 + t;
  bool valid = p < NPRI;
  float my_sl1 = 0.f, my_ce = 0.f;
  unsigned my_pos = 0;
  if (valid) {
    // per-prior match (recomputed, bit-identical to k_match's per-iou math)
    const float4 pv = ((const float4*)priors)[p];
    float px1 = pv.x - 0.5f * pv.z, py1 = pv.y - 0.5f * pv.w;
    float px2 = pv.x + 0.5f * pv.z, py2 = pv.y + 0.5f * pv.w;
    float parea = (px2 - px1) * (py2 - py1);
    float bov = 0.f; int bidx = 0;
#pragma unroll
    for (int g = 0; g < NGT; g++) {
      const float4 gv = ((const float4*)gtb)[b * NGT + g];
      float ix = fmaxf(fminf(px2, gv.z) - fmaxf(px1, gv.x), 0.f);
      float iy = fmaxf(fminf(py2, gv.w) - fmaxf(py1, gv.y), 0.f);
      float inter = ix * iy;
      float garea = (gv.z - gv.x) * (gv.w - gv.y);
      float iou = inter / (parea + garea - inter);
      if (iou > bov) { bov = iou; bidx = g; }
    }
    float o = bov; int g = bidx;
    // force-match (last-wins over ascending g); gtc reads are block-uniform s_loads
#pragma unroll
    for (int gg = 0; gg < NGT; gg++) {
      unsigned long long c64 = gtc[b * NGT + gg];
      unsigned pw = 0xFFFFFFFFu - (unsigned)(c64 & 0xFFFFFFFFull);
      if ((unsigned)p == pw) { o = 2.0f; g = gg; }
    }
    int c = gtl[b * NGT + g];
    if (o < F_POS_TH) c = -1;
    if (o < F_NEG_TH) c = 0;
    const float* r = rows + t * NCLS;  // stride 41 floats: odd -> conflict-free
    float s = 0.f, r0 = 0.f, rc = 0.f;
#pragma unroll
    for (int j = 0; j < NCLS; j++) {   // |x|<~7 for N(0,1): direct exp-sum safe in f32
      float v = r[j];
      s += __expf(v);
      if (j == 0) r0 = v;
      if (j == c) rc = v;
    }
    float lse = __logf(s);
    // key = lc float bits (bg only). Ties contribute equal sums -> no p-tiebreak needed.
    key[(size_t)b * NPRI + p] = (c == 0) ? __float_as_uint(lse - r0) : 0u;
    if (c > 0) {
      my_pos = 1;
      my_ce = lse - rc;
      const float4 gvb = ((const float4*)gtb)[b * NGT + g];
      float tx = ((gvb.x + gvb.z) * 0.5f - pv.x) / (0.1f * pv.z);
      float ty = ((gvb.y + gvb.w) * 0.5f - pv.y) / (0.1f * pv.w);
      float tw = __logf(fmaxf((gvb.z - gvb.x) / pv.z, 1e-8f)) / 0.2f;
      float th = __logf(fmaxf((gvb.w - gvb.y) / pv.w, 1e-8f)) / 0.2f;
      const float4 ld = ((const float4*)loc)[(size_t)b * NPRI + p];
      my_sl1 = smoothl1(ld.x - tx) + smoothl1(ld.y - ty)
             + smoothl1(ld.z - tw) + smoothl1(ld.w - th);
    }
  }
  // block-level reduction, one atomic per block per counter
  float vs = my_sl1, vc = my_ce; unsigned vp = my_pos;
#pragma unroll
  for (int off = 32; off; off >>= 1) {
    vs += __shfl_down(vs, off, 64);
    vc += __shfl_down(vc, off, 64);
    vp += __shfl_down(vp, off, 64);
  }
  if ((t & 63) == 0) { red_s[t >> 6] = vs; red_c[t >> 6] = vc; red_p[t >> 6] = vp; }
  __syncthreads();
  if (t == 0) {
    float ts = red_s[0] + red_s[1] + red_s[2] + red_s[3];
    float tc = red_c[0] + red_c[1] + red_c[2] + red_c[3];
    unsigned tp = red_p[0] + red_p[1] + red_p[2] + red_p[3];
    if (tp) atomicAdd(&npos[b], tp);
    if (ts != 0.f) atomicAdd(&sl1sum[b], ts);
    if (tc != 0.f) atomicAdd(&cepos[b], tc);
  }
}

// ---------------- radix-select pass over 32-bit keys: hist + last-block select ----------------
__global__ __launch_bounds__(256) void k_histfine(
    const unsigned* __restrict__ key,
    unsigned* __restrict__ hc_g, float* __restrict__ hs_g,
    unsigned* __restrict__ ticket, unsigned* __restrict__ prefix,
    unsigned* __restrict__ krem, const unsigned* __restrict__ npos,
    float* __restrict__ negsum, const float* __restrict__ sl1sum,
    const float* __restrict__ cepos, unsigned* __restrict__ final_tk,
    float* __restrict__ out, int shift, int pass) {
  __shared__ unsigned hc[NBIN];
  __shared__ float hs[NBIN];
  __shared__ unsigned pc[256]; __shared__ float ps[256];
  __shared__ unsigned sc[256]; __shared__ float ss[256];
  __shared__ int wA; __shared__ unsigned kexA; __shared__ float aboveA;
  __shared__ unsigned rk;
  int b = blockIdx.y;
  int t = threadIdx.x;
  for (int i = t; i < NBIN; i += 256) { hc[i] = 0; hs[i] = 0.f; }
  __syncthreads();
  unsigned long long pre = (unsigned long long)prefix[b] >> (shift + 12);
  for (int i = blockIdx.x * 256 + t; i < NPRI; i += HBLK * 256) {
    unsigned kk = key[(size_t)b * NPRI + i];
    if (((unsigned long long)kk >> (shift + 12)) == pre) {
      unsigned d = (kk >> shift) & 0xFFFu;
      atomicAdd(&hc[d], 1u);
      atomicAdd(&hs[d], __uint_as_float(kk));  // kk IS the lc float bits
    }
  }
  __syncthreads();
  unsigned base = ((unsigned)b) << 12;
  for (int i = t; i < NBIN; i += 256) {
    unsigned c = hc[i]; if (c) atomicAdd(&hc_g[base + i], c);
    float sv = hs[i];   if (sv != 0.f) atomicAdd(&hs_g[base + i], sv);
  }
  __threadfence();
  if (t == 0) rk = atomicAdd(&ticket[b], 1u);
  __syncthreads();
  if (rk != HBLK - 1) return;
  // ---- last block of this batch: select digit ----
  __threadfence();
  unsigned k = (pass == 0) ? min(3u * npos[b], (unsigned)(NPRI - 1)) : krem[b];
  for (int i = t; i < NBIN; i += 256) {  // pull global hist, self-clean for next pass/replay
    hc[i] = aload_u32(&hc_g[base + i]);
    hs[i] = aload_f32(&hs_g[base + i]);
    hc_g[base + i] = 0u;
    hs_g[base + i] = 0.f;
  }
  if (t == 0) { ticket[b] = 0; wA = -1; }
  __syncthreads();
  unsigned cs = 0; float fs = 0.f;
#pragma unroll
  for (int u = 0; u < 16; u++) { cs += hc[t * 16 + u]; fs += hs[t * 16 + u]; }
  pc[t] = cs; sc[t] = cs; ps[t] = fs; ss[t] = fs;
  __syncthreads();
  for (int off = 1; off < 256; off <<= 1) {  // suffix scans (count + sum)
    unsigned v = (t + off < 256) ? sc[t + off] : 0;
    float fv = (t + off < 256) ? ss[t + off] : 0.f;
    __syncthreads();
    sc[t] += v; ss[t] += fv;
    __syncthreads();
  }
  unsigned excl = sc[t] - pc[t];
  if (k > 0 && excl < k && k <= excl + pc[t]) {
    wA = t; kexA = excl; aboveA = ss[t] - ps[t];
  }
  __syncthreads();
  if (wA >= 0 && t < 64) {
    int w = wA; unsigned exw = kexA;
    unsigned v = (t < 16) ? hc[w * 16 + t] : 0;
    float fv = (t < 16) ? hs[w * 16 + t] : 0.f;
    unsigned sufv = v; float suff = fv;
#pragma unroll
    for (int off = 1; off < 16; off <<= 1) {
      unsigned x = __shfl_down(sufv, off, 64);
      float xf = __shfl_down(suff, off, 64);
      if (t + off < 16) { sufv += x; suff += xf; }
    }
    unsigned excl2 = exw + (sufv - v);
    if (t < 16 && excl2 < k && k <= excl2 + v) {
      float contrib = aboveA + (suff - fv);  // strictly-above items
      if (pass == 2) {
        contrib += (fv / (float)v) * (float)(k - excl2);  // threshold bin, exact under ties
      } else {
        prefix[b] |= ((unsigned)(w * 16 + t)) << shift;
        krem[b] = k - excl2;
      }
      if (contrib != 0.f) atomicAdd(&negsum[b], contrib);
    }
  }
  if (pass == 2) {  // globally-last block combines the final loss
    __syncthreads();
    if (t == 0) {
      __threadfence();
      unsigned r2 = atomicAdd(final_tk, 1u);
      if (r2 == BATCH - 1) {
        __threadfence();
        float lb = 0.f, ctot = 0.f;
        unsigned tp = 0;
        for (int bb = 0; bb < BATCH; bb++) {
          float ns = aload_f32(&negsum[bb]);
          lb += aload_f32(&sl1sum[bb]) / fmaxf((float)npos[bb], 1.f);
          tp += npos[bb];
          ctot += aload_f32(&cepos[bb]) + ns;
        }
        out[0] = (1.5f * lb + ctot / fmaxf((float)tp, 1.f)) / (float)BATCH;
        *final_tk = 0;  // self-clean for next replay
      }
    }
  }
}

extern "C" void kernel_launch(void* const* d_in, const int* in_sizes, int n_in,
                              void* d_out, int out_size, void* d_ws, size_t ws_size,
                              hipStream_t stream) {
  const float* loc = (const float*)d_in[0];
  const float* conf = (const float*)d_in[1];
  const float* priors = (const float*)d_in[2];
  const float* gtb = (const float*)d_in[3];
  const int* gtl = (const int*)d_in[4];
  char* ws = (char*)d_ws;
  unsigned* key = (unsigned*)(ws + OFF_KEY);
  unsigned long long* gtc = (unsigned long long*)(ws + OFF_GTC);
  unsigned* hc_g = (unsigned*)(ws + OFF_HC);
  float* hs_g = (float*)(ws + OFF_HS);
  unsigned* prefix = (unsigned*)(ws + OFF_PREF);
  unsigned* ticket = (unsigned*)(ws + OFF_TK);
  unsigned* krem = (unsigned*)(ws + OFF_KREM);
  unsigned* npos = (unsigned*)(ws + OFF_NPOS);
  float* sl1sum = (float*)(ws + OFF_SL1);
  float* cepos = (float*)(ws + OFF_CEP);
  float* negsum = (float*)(ws + OFF_NEG);
  unsigned* final_tk = (unsigned*)(ws + OFF_FTK);
  float* out = (float*)d_out;

  k_init<<<64, TPB, 0, stream>>>((unsigned*)(ws + OFF_ZERO), gtc);
  dim3 gridM(MCHUNK, BATCH * NGT);
  k_match<<<gridM, TPB, 0, stream>>>(priors, gtb, gtc);
  dim3 gridP(PBLK, BATCH);
  k_conf<<<gridP, TPB, 0, stream>>>(loc, conf, priors, gtb, gtl, gtc,
                                    key, npos, sl1sum, cepos);
  dim3 gridH(HBLK, BATCH);
  const int shifts[3] = {20, 8, 0};
  for (int pass = 0; pass < 3; pass++) {
    k_histfine<<<gridH, 256, 0, stream>>>(key, hc_g, hs_g, ticket, prefix, krem,
                                          npos, negsum, sl1sum, cepos, final_tk,
                                          out, shifts[pass], pass);
  }
}